// Round 4
// baseline (439.768 us; speedup 1.0000x reference)
//
#include <hip/hip_runtime.h>

// EvoBinarizedLayer: out[p,b,o] = x@W0 + (1-x)@W1  =  x@(W0-W1) + colsum_i(W1)
// x:[32,512,1024] {0,1} fp32; w:[2,32,1024,1024] {0,1} fp32; out fp32.
// Min traffic 384 MB -> ~59us floor @6.5TB/s. bf16 MFMA, exact.
//
// R4: software pipeline. R1-R3 all ~107us kernel despite different traffic
// structures -> bottleneck is the schedule: loads were drained by the
// barrier's implicit vmcnt(0) BEFORE LDS-write, so mem time (~3us/iter) and
// compute (~1us/iter) were fully serialized. New loop: STORE regs->LDS[cur];
// barrier; PREFETCH(kk+1) into regs; MFMA from LDS[cur]. Ping-pong LDS gives
// 1 barrier/iter; prefetch flies under MFMA and is drained only by the
// precise vmcnt at next iter's ds_write. BM=BN=128 keeps live VGPRs ~115
// (<128) so 2 blocks/CU co-schedule and cover each other's store/barrier gaps.

namespace {

constexpr int PP = 32;
constexpr int BB = 512;
constexpr int II = 1024;
constexpr int OO = 1024;

constexpr int BM = 128;   // b tile
constexpr int BN = 128;   // o tile
constexpr int BK = 32;    // k tile (= one 16x16x32 MFMA K)

constexpr int KPA = 40;   // A LDS row stride in bf16 elems (80B, 16B-aligned)

// B LDS addressing (bf16 elems): [o][k] with 16B pad every 4 rows.
__device__ __forceinline__ int boff(int o, int k) {
    return o * 40 + (o >> 2) * 8 + k;
}

typedef __attribute__((ext_vector_type(8))) short bf16x8;
typedef __attribute__((ext_vector_type(4))) float f32x4;

constexpr int A_BYTES = BM * KPA * 2;                 // 10240
constexpr int B_BYTES = (BN * 40 + (BN / 4) * 8) * 2; // 10752
constexpr int BUF_BYTES = A_BYTES + B_BYTES;          // 20992
constexpr int SMEM_BYTES = 2 * BUF_BYTES;             // 41984 -> 2 blocks = 84KB/CU

// fp32 -> bf16 by truncation: exact for {0,+-1}. Pack two into one u32 (lo=first).
__device__ __forceinline__ unsigned pk2(float lo, float hi) {
    return (__float_as_uint(lo) >> 16) | (__float_as_uint(hi) & 0xFFFF0000u);
}

__global__ __launch_bounds__(512, 4) void ebl_kernel(const float* __restrict__ x,
                                                     const float* __restrict__ w,
                                                     float* __restrict__ out) {
    __shared__ __align__(16) char smem[SMEM_BYTES];
    float* Scr    = (float*)smem;           // epilogue reuse: 16 x 128 partials
    float* ColSum = (float*)(smem + 8192);  // 128 floats

    const int t  = (int)threadIdx.x;     // 0..511
    const int l  = t & 63;
    const int wv = t >> 6;       // wave 0..7
    const int wm = wv & 1;       // wave m (b) tile: rows wm*64..+63
    const int wn = wv >> 1;      // wave n (o) tile: cols wn*32..+31
    const int lq = l >> 4;       // quad
    const int ln = l & 15;

    // XCD-aware bijective swizzle (1024 % 8 == 0): XCD k (= bid%8) gets works
    // [128k, 128k+128) = 4 p-slices x (4 b-blocks x 8 o-blocks); all sharers
    // of any x panel (8-way) / w panel (4-way) are co-XCD and ~concurrent.
    const int bid = (int)blockIdx.x;
    const int wid = (bid & 7) * 128 + (bid >> 3);
    const int p   = wid >> 5;              // 0..31
    const int rem = wid & 31;
    const int b0  = (rem & 3) * BM;        // 4 b-blocks
    const int o0  = (rem >> 2) * BN;       // 8 o-blocks

    const float* xp  = x + ((size_t)p * BB + b0) * II;
    const float* w0p = w + (size_t)p * II * OO;
    const float* w1p = w + (size_t)(PP + p) * II * OO;

    // A staging: 2 loads/thread: rows a_row, a_row+64; 8 lanes per 32-float row seg.
    const int a_row = t >> 3;            // 0..63
    const int a_col = (t & 7) * 4;
    // B staging: thread covers k rows bk0, bk0+1 at o-group og..og+3 (both tensors).
    const int bk0 = 2 * (t >> 5);        // 0,2,..,30
    const int og  = (t & 31) * 4;        // 0..124

    // Fragment LDS read offsets are k-loop invariant (buffer base added in-loop).
    int a_rd[4], b_rd[2];
#pragma unroll
    for (int mt = 0; mt < 4; ++mt)
        a_rd[mt] = (wm * 64 + mt * 16 + ln) * KPA + lq * 8;
#pragma unroll
    for (int nt = 0; nt < 2; ++nt)
        b_rd[nt] = boff(wn * 32 + nt * 16 + ln, lq * 8);

    f32x4 acc[4][2];
#pragma unroll
    for (int mt = 0; mt < 4; ++mt)
#pragma unroll
        for (int nt = 0; nt < 2; ++nt)
            acc[mt][nt] = (f32x4){0.f, 0.f, 0.f, 0.f};

    f32x4 csum = (f32x4){0.f, 0.f, 0.f, 0.f};  // colsum(W1) partial, o = og..og+3

    const float* xa0  = xp + (size_t)a_row * II + a_col;
    const float* xa1  = xa0 + (size_t)64 * II;
    const float* wb00 = w0p + (size_t)bk0 * OO + o0 + og;  // W0 row bk0
    const float* wb01 = wb00 + OO;                          // W0 row bk0+1
    const float* wb10 = w1p + (size_t)bk0 * OO + o0 + og;  // W1 row bk0
    const float* wb11 = wb10 + OO;                          // W1 row bk0+1

    // ---- prologue: prefetch k-chunk 0 into registers ----
    f32x4 a0  = *(const f32x4*)(xa0);
    f32x4 a1  = *(const f32x4*)(xa1);
    f32x4 q00 = *(const f32x4*)(wb00);
    f32x4 q01 = *(const f32x4*)(wb01);
    f32x4 q10 = *(const f32x4*)(wb10);
    f32x4 q11 = *(const f32x4*)(wb11);

    for (int kk = 0; kk < II; kk += BK) {
        char* buf = smem + ((kk >> 5) & 1) * BUF_BYTES;
        unsigned short* As = (unsigned short*)buf;
        unsigned short* Bs = (unsigned short*)(buf + A_BYTES);

        // ---- STORE: regs(kk) -> LDS[cur] (precise vmcnt waits happen here) ----
        *(uint2*)(&As[a_row * KPA + a_col]) =
            make_uint2(pk2(a0.x, a0.y), pk2(a0.z, a0.w));
        *(uint2*)(&As[(a_row + 64) * KPA + a_col]) =
            make_uint2(pk2(a1.x, a1.y), pk2(a1.z, a1.w));
        f32x4 d0 = q00 - q10;   // W0-W1, k = bk0
        f32x4 d1 = q01 - q11;   // k = bk0+1
        csum += q10;
        csum += q11;
#pragma unroll
        for (int c = 0; c < 4; ++c)
            *(unsigned*)(&Bs[boff(og + c, bk0)]) = pk2(d0[c], d1[c]);

        __syncthreads();

        // ---- PREFETCH k-chunk kk+BK: flies under the MFMA phase ----
        const int kn = kk + BK;
        if (kn < II) {
            a0  = *(const f32x4*)(xa0 + kn);
            a1  = *(const f32x4*)(xa1 + kn);
            q00 = *(const f32x4*)(wb00 + (size_t)kn * OO);
            q01 = *(const f32x4*)(wb01 + (size_t)kn * OO);
            q10 = *(const f32x4*)(wb10 + (size_t)kn * OO);
            q11 = *(const f32x4*)(wb11 + (size_t)kn * OO);
        }

        // ---- MFMA: wave tile 64x32, one K=32 step ----
        bf16x8 bfm[2];
#pragma unroll
        for (int nt = 0; nt < 2; ++nt)
            bfm[nt] = *(const bf16x8*)(&Bs[b_rd[nt]]);
#pragma unroll
        for (int mt = 0; mt < 4; ++mt) {
            bf16x8 af = *(const bf16x8*)(&As[a_rd[mt]]);
#pragma unroll
            for (int nt = 0; nt < 2; ++nt)
                acc[mt][nt] = __builtin_amdgcn_mfma_f32_16x16x32_bf16(
                    af, bfm[nt], acc[mt][nt], 0, 0, 0);
        }
        // next iter's STORE targets the other buffer; its barrier orders
        // this iter's ds_reads (consumed before barrier) vs overwrite. safe.
    }

    // ---- colsum(W1) reduction: 16 k-group partials -> 128 column sums ----
    __syncthreads();
    *(f32x4*)(&Scr[(t >> 5) * 128 + og]) = csum;
    __syncthreads();
    if (t < 128) {
        float s = 0.f;
#pragma unroll
        for (int q = 0; q < 16; ++q) s += Scr[q * 128 + t];
        ColSum[t] = s;
    }
    __syncthreads();

    // ---- epilogue: C/D layout col=lane&15, row=quad*4+reg (m89/m91-verified) ----
    float* op = out + (size_t)p * BB * OO + o0;
#pragma unroll
    for (int nt = 0; nt < 2; ++nt) {
        const int ocol = wn * 32 + nt * 16 + ln;
        const float cs = ColSum[ocol];
#pragma unroll
        for (int mt = 0; mt < 4; ++mt) {
            const int row = b0 + wm * 64 + mt * 16 + lq * 4;
#pragma unroll
            for (int r = 0; r < 4; ++r)
                op[(size_t)(row + r) * OO + ocol] = acc[mt][nt][r] + cs;
        }
    }
}

}  // namespace

extern "C" void kernel_launch(void* const* d_in, const int* in_sizes, int n_in,
                              void* d_out, int out_size, void* d_ws, size_t ws_size,
                              hipStream_t stream) {
    const float* x = (const float*)d_in[0];
    const float* w = (const float*)d_in[1];
    float* out = (float*)d_out;
    dim3 grid(PP * (BB / BM) * (OO / BN), 1, 1);  // 1024 blocks, 2/CU resident
    ebl_kernel<<<grid, dim3(512, 1, 1), 0, stream>>>(x, w, out);
}

// Round 5
// 435.162 us; speedup vs baseline: 1.0106x; 1.0106x over previous
//
#include <hip/hip_runtime.h>

// EvoBinarizedLayer: out[p,b,o] = x@W0 + (1-x)@W1  =  x@(W0-W1) + colsum_i(W1)
// x:[32,512,1024] {0,1} fp32; w:[2,32,1024,1024] {0,1} fp32; out fp32.
// bf16 MFMA, exact (all values in {-1,0,1}; truncation lossless).
//
// R5 = R1 structure (best measured, 430.8us) + non-temporal out stores.
// Roofline model (R0-R4 evidence): kernel floor = compulsory 384 MB
// (x 64 + w 256 + out 64, cold each iter) + ~288 MB dirty poison-fill
// residue (L2 32 MB + LLC 256 MB) draining during the kernel
// => ~105us @ 6.4 TB/s. R1-R4 all measured 107-112us kernel despite four
// orthogonal restructurings (traffic shaping, 2 blocks/CU, reg-prefetch
// dbuf pipeline) -> we are at this composite floor. NT stores are the last
// riskless lever (skip write-allocate on out lines).

namespace {

constexpr int PP = 32;
constexpr int BB = 512;
constexpr int II = 1024;
constexpr int OO = 1024;

constexpr int BM = 256;   // b tile
constexpr int BN = 256;   // o tile
constexpr int BK = 32;    // k tile (= one 16x16x32 MFMA K)

constexpr int KPA = 40;   // A LDS row stride in bf16 elems (80B, 16B-aligned)

// B LDS addressing (bf16 elems): [o][k] with 16B pad every 4 rows.
__device__ __forceinline__ int boff(int o, int k) {
    return o * 40 + (o >> 2) * 8 + k;
}

typedef __attribute__((ext_vector_type(8))) short bf16x8;
typedef __attribute__((ext_vector_type(4))) float f32x4;

constexpr int A_BYTES = BM * KPA * 2;                 // 20480
constexpr int B_BYTES = (BN * 40 + (BN / 4) * 8) * 2; // 21504
constexpr int SMEM_BYTES = A_BYTES + B_BYTES;         // 41984 < 64KB

// fp32 -> bf16 by truncation: exact for {0,+-1}. Pack two into one u32 (lo=first).
__device__ __forceinline__ unsigned pk2(float lo, float hi) {
    return (__float_as_uint(lo) >> 16) | (__float_as_uint(hi) & 0xFFFF0000u);
}

__global__ __launch_bounds__(1024) void ebl_kernel(const float* __restrict__ x,
                                                   const float* __restrict__ w,
                                                   float* __restrict__ out) {
    __shared__ __align__(16) char smem[SMEM_BYTES];
    unsigned short* As = (unsigned short*)smem;            // [BM][KPA] bf16, [b][k]
    unsigned short* Bs = (unsigned short*)(smem + A_BYTES);// boff-layout bf16, [o][k]
    float* Scr    = (float*)smem;            // reused after k-loop: 16 waves x 256 o
    float* ColSum = (float*)(smem + 16384);  // 256 floats (still inside A region)

    const int t  = (int)threadIdx.x;
    const int l  = t & 63;
    const int wv = t >> 6;       // wave 0..15
    const int wm = wv & 3;       // wave m (b) tile
    const int wn = wv >> 2;      // wave n (o) tile
    const int lq = l >> 4;       // quad
    const int ln = l & 15;

    // XCD-aware swizzle: XCD k (= bid%8, round-robin dispatch) gets the
    // contiguous work chunk [32k, 32k+32), p-major: 4 whole p-slices per XCD.
    const int bid = (int)blockIdx.x;
    const int wid = (bid & 7) * 32 + (bid >> 3);
    const int p   = wid >> 3;               // 0..31, 4 per XCD chunk
    const int o0  = ((wid >> 1) & 3) * BN;  // o-block
    const int b0  = (wid & 1) * BM;         // b-block

    const float* xp  = x + ((size_t)p * BB + b0) * II;
    const float* w0p = w + (size_t)p * II * OO;
    const float* w1p = w + (size_t)(PP + p) * II * OO;

    // A staging: 2 loads/thread: rows a_row, a_row+128; 8 lanes cover a 32-float row seg.
    const int a_row = t >> 3;
    const int a_col = (t & 7) * 4;
    // B staging: wave wv loads w rows 2wv, 2wv+1; 64 lanes cover a full 1KB row.
    const int b_colg = 4 * l;

    // Fragment LDS read offsets are k-loop invariant.
    int a_rd[4], b_rd[4];
#pragma unroll
    for (int mt = 0; mt < 4; ++mt)
        a_rd[mt] = (wm * 64 + mt * 16 + ln) * KPA + lq * 8;
#pragma unroll
    for (int nt = 0; nt < 4; ++nt)
        b_rd[nt] = boff(wn * 64 + nt * 16 + ln, lq * 8);

    f32x4 acc[4][4];
#pragma unroll
    for (int mt = 0; mt < 4; ++mt)
#pragma unroll
        for (int nt = 0; nt < 4; ++nt)
            acc[mt][nt] = (f32x4){0.f, 0.f, 0.f, 0.f};

    f32x4 csum = (f32x4){0.f, 0.f, 0.f, 0.f};  // per-lane colsum(W1) partial, o=4l..4l+3

    const float* xa0  = xp + (size_t)a_row * II + a_col;
    const float* xa1  = xp + (size_t)(a_row + 128) * II + a_col;
    const float* wb00 = w0p + (size_t)(2 * wv) * OO + o0 + b_colg;
    const float* wb01 = w0p + (size_t)(2 * wv + 1) * OO + o0 + b_colg;
    const float* wb10 = w1p + (size_t)(2 * wv) * OO + o0 + b_colg;
    const float* wb11 = w1p + (size_t)(2 * wv + 1) * OO + o0 + b_colg;

    for (int kk = 0; kk < II; kk += BK) {
        // ---- global loads (fp32, dwordx4, fully coalesced) ----
        f32x4 a0  = *(const f32x4*)(xa0 + kk);
        f32x4 a1  = *(const f32x4*)(xa1 + kk);
        f32x4 p00 = *(const f32x4*)(wb00 + (size_t)kk * OO);
        f32x4 p01 = *(const f32x4*)(wb01 + (size_t)kk * OO);
        f32x4 p10 = *(const f32x4*)(wb10 + (size_t)kk * OO);
        f32x4 p11 = *(const f32x4*)(wb11 + (size_t)kk * OO);

        __syncthreads();  // prior iteration's LDS reads complete

        // ---- A: truncate-convert to bf16, k-contiguous b64 writes ----
        *(uint2*)(&As[a_row * KPA + a_col]) =
            make_uint2(pk2(a0.x, a0.y), pk2(a0.z, a0.w));
        *(uint2*)(&As[(a_row + 128) * KPA + a_col]) =
            make_uint2(pk2(a1.x, a1.y), pk2(a1.z, a1.w));

        // ---- B: diff = W0-W1 (in {-1,0,1}), colsum(W1), register transpose ----
        f32x4 d0 = p00 - p10;   // k = 2wv
        f32x4 d1 = p01 - p11;   // k = 2wv+1
        csum += p10;
        csum += p11;
        const int kloc = 2 * wv;
#pragma unroll
        for (int c = 0; c < 4; ++c)
            *(unsigned*)(&Bs[boff(b_colg + c, kloc)]) = pk2(d0[c], d1[c]);

        __syncthreads();

        // ---- MFMA: wave tile 64x64, one K=32 step ----
        bf16x8 af[4], bfm[4];
#pragma unroll
        for (int mt = 0; mt < 4; ++mt)
            af[mt] = *(const bf16x8*)(&As[a_rd[mt]]);
#pragma unroll
        for (int nt = 0; nt < 4; ++nt)
            bfm[nt] = *(const bf16x8*)(&Bs[b_rd[nt]]);
#pragma unroll
        for (int mt = 0; mt < 4; ++mt)
#pragma unroll
            for (int nt = 0; nt < 4; ++nt)
                acc[mt][nt] = __builtin_amdgcn_mfma_f32_16x16x32_bf16(
                    af[mt], bfm[nt], acc[mt][nt], 0, 0, 0);
    }

    // ---- colsum(W1) reduction: 16 per-wave partials -> 256 column sums ----
    __syncthreads();                       // last MFMA reads done; reuse A region
    *(f32x4*)(&Scr[wv * 256 + l * 4]) = csum;
    __syncthreads();
    if (t < 256) {
        float s = 0.f;
#pragma unroll
        for (int ww = 0; ww < 16; ++ww) s += Scr[ww * 256 + t];
        ColSum[t] = s;
    }
    __syncthreads();

    // ---- epilogue: C/D layout col=lane&15, row=quad*4+reg (m89/m91-verified) ----
    // Non-temporal: out is write-once, never re-read by us; skip L2/LLC
    // allocation so the poison-residue drain and input reads keep the cache.
    float* op = out + (size_t)p * BB * OO + o0;
#pragma unroll
    for (int nt = 0; nt < 4; ++nt) {
        const int ocol = wn * 64 + nt * 16 + ln;
        const float cs = ColSum[ocol];
#pragma unroll
        for (int mt = 0; mt < 4; ++mt) {
            const int row = b0 + wm * 64 + mt * 16 + lq * 4;
#pragma unroll
            for (int r = 0; r < 4; ++r)
                __builtin_nontemporal_store(acc[mt][nt][r] + cs,
                                            &op[(size_t)(row + r) * OO + ocol]);
        }
    }
}

}  // namespace

extern "C" void kernel_launch(void* const* d_in, const int* in_sizes, int n_in,
                              void* d_out, int out_size, void* d_ws, size_t ws_size,
                              hipStream_t stream) {
    const float* x = (const float*)d_in[0];
    const float* w = (const float*)d_in[1];
    float* out = (float*)d_out;
    dim3 grid(PP * (BB / BM) * (OO / BN), 1, 1);  // 256 blocks = 1/CU
    ebl_kernel<<<grid, dim3(1024, 1, 1), 0, stream>>>(x, w, out);
}